// Round 9
// baseline (336.132 us; speedup 1.0000x reference)
//
#include <hip/hip_runtime.h>
#include <hip/hip_cooperative_groups.h>
#include <math.h>

namespace cg = cooperative_groups;

// Problem constants (from reference)
#define GRID_N 544          // NUM_GRID = ceil(128*4.2/16)*16 = 68 * 8
#define BATCH  8
#define NPTS   2048
#define MPTS   2048
#define XMIN_F (-2.1f)
#define STEP_F (4.2f / 543.0f)   // linspace step, endpoint inclusive

typedef float v4f __attribute__((ext_vector_type(4)));

// Workspace layout (floats):
// prm: [0..7]=a_mean, [8..15]=a_sig, [16..79]=S, [80..87]=u, [88]=s0,
//      [89]=all-16-scales-identical flag
#define PRM_OFF 0
#define H_OFF   128
#define FST_OFF (H_OFF + BATCH*GRID_N*8)
#define P_OFF   (FST_OFF + BATCH*8*MPTS)
#define CM_OFF  (P_OFF + BATCH*MPTS*8)

// Session budget (R5/R6 duplicate-launch + R7/R8 shape experiments):
//   T_cov ~21us (write floor), harness-fixed ~146us, and ~25-40us of
//   SHAPE-INVARIANT per-launch cost (enc/feat reshapes 4x-8x: all +-2us).
// R9: eliminate kernel boundaries entirely.  R2's fused attempt failed
// from an identified bug: __launch_bounds__(256,4) forced VGPR=64 while
// phase C holds 64 VGPRs of accumulators alone -> scratch spills -> 10x
// under floor.  v2 fixes: (1) launch_bounds(256,2) [VGPR<=256, no spill],
// (2) phase C = R4's proven 8-row/8-store-burst body, (3) phase E = R8's
// LDS-staged 8g/unit shape, phase F = R4's proven shape.

__global__ __launch_bounds__(256, 2) void k_fused(
    const float* __restrict__ x, const float* __restrict__ y,
    const float* __restrict__ x_out,
    const float* __restrict__ enc_sigma, const float* __restrict__ enc_W,
    const float* __restrict__ enc_b, const float* __restrict__ rho_W,
    const float* __restrict__ rho_b, const float* __restrict__ mean_sigma,
    const float* __restrict__ mean_W, const float* __restrict__ mean_b,
    const float* __restrict__ sig_sigma, const float* __restrict__ sig_W,
    const float* __restrict__ sig_b, const float* __restrict__ noise_scale,
    float* __restrict__ prm, float* __restrict__ h_out,
    float* __restrict__ fSt, float* __restrict__ Pv, float* __restrict__ cm,
    float* __restrict__ mean_out, float* __restrict__ cov) {
  const int bid = blockIdx.x, t = threadIdx.x, nb = gridDim.x;
  __shared__ float sbuf[256 * 17];   // phase E: xs/ys (16KB); F: red (17.4KB)

  // ---------------- phase E: encoder (545 units) ----------------
  for (int u = bid; u < 545; u += nb) {
    if (u == 544) {
      // ---- parameter unit ----
      float* part = sbuf;
      {
        int pair = t >> 2, q = t & 3;
        int i = pair >> 3, j = pair & 7;
        float s = 0.f;
        int k0 = q * 256;
        for (int k = k0; k < k0 + 256; ++k) s += sig_W[i*1024+k] * sig_W[j*1024+k];
        part[t] = s;
        __syncthreads();
        if (q == 0) prm[16 + pair] = part[t] + part[t+1] + part[t+2] + part[t+3];
        __syncthreads();
      }
      {
        int ch = t >> 5, lane = t & 31;
        float s = 0.f;
        for (int k = lane; k < 1024; k += 32) s += sig_W[ch*1024+k] * sig_b[k];
        part[t] = s;
        __syncthreads();
        if (lane == 0) {
          float acc = 0.f;
          for (int k = 0; k < 32; ++k) acc += part[(ch<<5)+k];
          prm[80 + ch] = acc;
        }
        __syncthreads();
      }
      if (t < 32) {
        float v = 0.f;
        for (int k = t; k < 1024; k += 32) v += sig_b[k] * sig_b[k];
        part[t] = v;
      }
      __syncthreads();
      if (t == 0) {
        float v = 0.f;
        for (int k = 0; k < 32; ++k) v += part[k];
        prm[88] = v;
      } else if (t == 1) {
        bool f = true;
        for (int c = 0; c < 8; ++c) {
          prm[c]     = 0.5f * __expf(-2.f * mean_sigma[c]);
          prm[8 + c] = 0.5f * __expf(-2.f * sig_sigma[c]);
          if (mean_sigma[c] != mean_sigma[0] || sig_sigma[c] != sig_sigma[0]) f = false;
        }
        if (mean_sigma[0] != sig_sigma[0]) f = false;
        prm[89] = f ? 1.f : 0.f;
      }
      __syncthreads();
    } else {
      // ---- encode unit: (b, gt) covers 8 g's, x/y staged in LDS ----
      int b = u / 68, gt = u - b * 68;
      float* xs = sbuf;
      float* ys = sbuf + NPTS;
      __syncthreads();   // protect prior unit's LDS reads
      {
        const float4* x4 = (const float4*)(x + (size_t)b * NPTS);
        const float4* y4 = (const float4*)(y + (size_t)b * NPTS);
        float4* xs4 = (float4*)xs;
        float4* ys4 = (float4*)ys;
        #pragma unroll
        for (int i = 0; i < 2; ++i) {
          int n = i * 256 + t;
          xs4[n] = x4[n];
          ys4[n] = y4[n];
        }
      }
      __syncthreads();
      float es0 = enc_sigma[0], es1 = enc_sigma[1];
      float a0 = 0.5f * __expf(-2.f * es0);
      float a1 = 0.5f * __expf(-2.f * es1);
      bool uni = (es0 == es1);
      int wave = t >> 6, lane = t & 63;
      #pragma unroll 1
      for (int gi = 0; gi < 2; ++gi) {
        int g = gt * 8 + wave * 2 + gi;
        float gv = XMIN_F + (float)g * STEP_F;
        float s0 = 0.f, s1 = 0.f;
        #pragma unroll 4
        for (int k = 0; k < 32; ++k) {
          int n = lane + (k << 6);     // stride-64: 2 lanes/bank (free)
          float xv = xs[n], yv = ys[n];
          float dx = xv - gv;
          float d = dx * dx;
          float w = __expf(-d * a0);
          s0 += w;
          s1 += yv * (uni ? w : __expf(-d * a1));
        }
        #pragma unroll
        for (int off = 32; off > 0; off >>= 1) {
          s0 += __shfl_down(s0, off);
          s1 += __shfl_down(s1, off);
        }
        if (lane == 0) {
          float den = s0;
          float F0 = den, F1 = s1 / (den + 1e-8f);
          float hh[8];
          #pragma unroll
          for (int jj = 0; jj < 8; ++jj) {
            float z = F0 * enc_W[jj] + F1 * enc_W[8 + jj] + enc_b[jj];
            hh[jj] = 1.f / (1.f + __expf(-z));
          }
          #pragma unroll
          for (int jj = 0; jj < 8; ++jj) {
            float v = rho_b[jj];
            #pragma unroll
            for (int ii = 0; ii < 8; ++ii) v += hh[ii] * rho_W[ii*8 + jj];
            h_out[((size_t)b * GRID_N + g) * 8 + jj] = v;
          }
        }
      }
    }
  }
  cg::this_grid().sync();

  // ---------------- phase F: decoder feats (256 units, R4 shape) ----------
  bool fsc = prm[89] != 0.f;
  for (int u = bid; u < 256; u += nb) {
    int b = u >> 5, mblk = u & 31;
    int ml = t & 63, slice = t >> 6;
    int m = mblk * 64 + ml;
    float xo = x_out[(size_t)b * MPTS + m];
    float accm[8] = {0,0,0,0,0,0,0,0};
    float accs[8] = {0,0,0,0,0,0,0,0};
    const float* hb = h_out + (size_t)b * GRID_N * 8;
    const float4* h4 = (const float4*)hb;
    int gbase = slice * 136;
    if (fsc) {
      float a = prm[0];
      for (int gg = 0; gg < 136; ++gg) {
        int g = gbase + gg;
        float gv = XMIN_F + (float)g * STEP_F;
        float dx = gv - xo;
        float w = __expf(-(dx*dx) * a);
        float4 h0 = h4[g*2], h1 = h4[g*2+1];
        accm[0] += h0.x * w; accm[1] += h0.y * w;
        accm[2] += h0.z * w; accm[3] += h0.w * w;
        accm[4] += h1.x * w; accm[5] += h1.y * w;
        accm[6] += h1.z * w; accm[7] += h1.w * w;
      }
    } else {
      float am[8], asg[8];
      #pragma unroll
      for (int c = 0; c < 8; ++c) { am[c] = prm[c]; asg[c] = prm[8 + c]; }
      for (int gg = 0; gg < 136; ++gg) {
        int g = gbase + gg;
        float gv = XMIN_F + (float)g * STEP_F;
        float dx = gv - xo;
        float d = dx * dx;
        #pragma unroll
        for (int c = 0; c < 8; ++c) {
          float hv = hb[g*8 + c];
          accm[c] += hv * __expf(-d * am[c]);
          accs[c] += hv * __expf(-d * asg[c]);
        }
      }
    }
    __syncthreads();   // protect sbuf reuse (prior unit / phase E)
    #pragma unroll
    for (int c = 0; c < 8; ++c) {
      sbuf[t*17 + c] = accm[c];
      if (!fsc) sbuf[t*17 + 8 + c] = accs[c];
    }
    __syncthreads();
    if (t < 64) {
      int mm = mblk * 64 + t;
      float fm[8], fs[8];
      #pragma unroll
      for (int c = 0; c < 8; ++c) {
        fm[c] = sbuf[t*17+c] + sbuf[(t+64)*17+c] + sbuf[(t+128)*17+c] + sbuf[(t+192)*17+c];
      }
      if (fsc) {
        #pragma unroll
        for (int c = 0; c < 8; ++c) fs[c] = fm[c];
      } else {
        #pragma unroll
        for (int c = 0; c < 8; ++c) {
          fs[c] = sbuf[t*17+8+c] + sbuf[(t+64)*17+8+c] + sbuf[(t+128)*17+8+c] + sbuf[(t+192)*17+8+c];
        }
      }
      float mv = mean_b[0];
      #pragma unroll
      for (int c = 0; c < 8; ++c) mv += fm[c] * mean_W[c];
      mean_out[(size_t)b * MPTS + mm] = mv;
      float cmv = prm[88];
      #pragma unroll
      for (int c = 0; c < 8; ++c) cmv += fs[c] * prm[80 + c];
      cm[(size_t)b * MPTS + mm] = cmv;
      size_t base = ((size_t)b * MPTS + mm) * 8;
      #pragma unroll
      for (int c2 = 0; c2 < 8; ++c2) {
        float p = prm[80 + c2];
        #pragma unroll
        for (int c = 0; c < 8; ++c) p += fs[c] * prm[16 + c*8 + c2];
        Pv[base + c2] = p;
      }
      float* fp = fSt + (size_t)b * 8 * MPTS + mm;
      #pragma unroll
      for (int c = 0; c < 8; ++c) fp[c * MPTS] = fs[c];
    }
  }
  cg::this_grid().sync();

  // ---------------- phase C: covariance (4096 units, R4 body) -------------
  float noise = __expf(noise_scale[0]);
  for (int u = bid; u < BATCH * 512; u += nb) {
    int b = u >> 9, idx = u & 511;
    int half = idx & 1, rt = idx >> 1;     // rt in [0,256)
    int col = half * 1024 + 4 * t;
    int row0 = rt * 8;
    v4f fn[8];
    const float* fb_ = fSt + (size_t)b * 8 * MPTS;
    #pragma unroll
    for (int c = 0; c < 8; ++c)
      fn[c] = *(const v4f*)(fb_ + c * MPTS + col);
    const float* Pr = Pv + ((size_t)b * MPTS + row0) * 8;   // wave-uniform
    const float* Cr = cm + (size_t)b * MPTS + row0;
    v4f o[8];
    #pragma unroll
    for (int i = 0; i < 8; ++i) {
      float cc = Cr[i];
      float a0 = cc, a1 = cc, a2 = cc, a3 = cc;
      #pragma unroll
      for (int c = 0; c < 8; ++c) {
        float p = Pr[i * 8 + c];
        a0 += p * fn[c].x; a1 += p * fn[c].y;
        a2 += p * fn[c].z; a3 += p * fn[c].w;
      }
      int mg = row0 + i;
      if (mg == col)     a0 += noise;
      if (mg == col + 1) a1 += noise;
      if (mg == col + 2) a2 += noise;
      if (mg == col + 3) a3 += noise;
      o[i].x = a0; o[i].y = a1; o[i].z = a2; o[i].w = a3;
    }
    #pragma unroll
    for (int i = 0; i < 8; ++i) {
      v4f* dst = (v4f*)(cov + ((size_t)b * MPTS + row0 + i) * MPTS + col);
      __builtin_nontemporal_store(o[i], dst);
    }
  }
}

// =================================================================
// Fallback 3-kernel path (R8 = best-measured class, ~211us)
// =================================================================
__global__ __launch_bounds__(256) void k_encode(
    const float* __restrict__ x, const float* __restrict__ y,
    const float* __restrict__ enc_sigma,
    const float* __restrict__ enc_W, const float* __restrict__ enc_b,
    const float* __restrict__ rho_W, const float* __restrict__ rho_b,
    const float* __restrict__ mean_sigma, const float* __restrict__ sig_sigma,
    const float* __restrict__ sig_W, const float* __restrict__ sig_b,
    float* __restrict__ prm, float* __restrict__ h_out) {
  int b = blockIdx.y, gt = blockIdx.x, t = threadIdx.x;
  if (gt == 68) {
    if (b != 0) return;
    __shared__ float part[256];
    {
      int pair = t >> 2, q = t & 3;
      int i = pair >> 3, j = pair & 7;
      float s = 0.f;
      int k0 = q * 256;
      for (int k = k0; k < k0 + 256; ++k) s += sig_W[i*1024+k] * sig_W[j*1024+k];
      part[t] = s;
      __syncthreads();
      if (q == 0) prm[16 + pair] = part[t] + part[t+1] + part[t+2] + part[t+3];
      __syncthreads();
    }
    {
      int ch = t >> 5, lane = t & 31;
      float s = 0.f;
      for (int k = lane; k < 1024; k += 32) s += sig_W[ch*1024+k] * sig_b[k];
      part[t] = s;
      __syncthreads();
      if (lane == 0) {
        float acc = 0.f;
        for (int k = 0; k < 32; ++k) acc += part[(ch<<5)+k];
        prm[80 + ch] = acc;
      }
      __syncthreads();
    }
    if (t < 32) {
      float v = 0.f;
      for (int k = t; k < 1024; k += 32) v += sig_b[k] * sig_b[k];
      part[t] = v;
    }
    __syncthreads();
    if (t == 0) {
      float v = 0.f;
      for (int k = 0; k < 32; ++k) v += part[k];
      prm[88] = v;
    } else if (t == 1) {
      bool f = true;
      for (int c = 0; c < 8; ++c) {
        prm[c]     = 0.5f * __expf(-2.f * mean_sigma[c]);
        prm[8 + c] = 0.5f * __expf(-2.f * sig_sigma[c]);
        if (mean_sigma[c] != mean_sigma[0] || sig_sigma[c] != sig_sigma[0]) f = false;
      }
      if (mean_sigma[0] != sig_sigma[0]) f = false;
      prm[89] = f ? 1.f : 0.f;
    }
    return;
  }
  __shared__ float xs[NPTS], ys[NPTS];
  {
    const float4* x4 = (const float4*)(x + (size_t)b * NPTS);
    const float4* y4 = (const float4*)(y + (size_t)b * NPTS);
    float4* xs4 = (float4*)xs;
    float4* ys4 = (float4*)ys;
    #pragma unroll
    for (int i = 0; i < 2; ++i) {
      int n = i * 256 + t;
      xs4[n] = x4[n];
      ys4[n] = y4[n];
    }
  }
  __syncthreads();
  float es0 = enc_sigma[0], es1 = enc_sigma[1];
  float a0 = 0.5f * __expf(-2.f * es0);
  float a1 = 0.5f * __expf(-2.f * es1);
  bool uni = (es0 == es1);
  int wave = t >> 6, lane = t & 63;
  #pragma unroll 1
  for (int gi = 0; gi < 2; ++gi) {
    int g = gt * 8 + wave * 2 + gi;
    float gv = XMIN_F + (float)g * STEP_F;
    float s0 = 0.f, s1 = 0.f;
    #pragma unroll 4
    for (int k = 0; k < 32; ++k) {
      int n = lane + (k << 6);
      float xv = xs[n], yv = ys[n];
      float dx = xv - gv;
      float d = dx * dx;
      float w = __expf(-d * a0);
      s0 += w;
      s1 += yv * (uni ? w : __expf(-d * a1));
    }
    #pragma unroll
    for (int off = 32; off > 0; off >>= 1) {
      s0 += __shfl_down(s0, off);
      s1 += __shfl_down(s1, off);
    }
    if (lane == 0) {
      float den = s0;
      float F0 = den, F1 = s1 / (den + 1e-8f);
      float hh[8];
      #pragma unroll
      for (int jj = 0; jj < 8; ++jj) {
        float z = F0 * enc_W[jj] + F1 * enc_W[8 + jj] + enc_b[jj];
        hh[jj] = 1.f / (1.f + __expf(-z));
      }
      #pragma unroll
      for (int jj = 0; jj < 8; ++jj) {
        float v = rho_b[jj];
        #pragma unroll
        for (int ii = 0; ii < 8; ++ii) v += hh[ii] * rho_W[ii*8 + jj];
        h_out[((size_t)b * GRID_N + g) * 8 + jj] = v;
      }
    }
  }
}

__global__ __launch_bounds__(256) void k_feat(
    const float* __restrict__ x_out, const float* __restrict__ mean_W,
    const float* __restrict__ mean_b, const float* __restrict__ prm,
    const float* __restrict__ h, float* __restrict__ mean_out,
    float* __restrict__ fSt, float* __restrict__ Pv, float* __restrict__ cm) {
  int b = blockIdx.y, t = threadIdx.x;
  int ml = t & 63, slice = t >> 6;
  int m = blockIdx.x * 64 + ml;
  float xo = x_out[(size_t)b * MPTS + m];
  bool fused = prm[89] != 0.f;
  float accm[8] = {0,0,0,0,0,0,0,0};
  float accs[8] = {0,0,0,0,0,0,0,0};
  const float* hb = h + (size_t)b * GRID_N * 8;
  const float4* h4 = (const float4*)hb;
  int gbase = slice * 136;
  if (fused) {
    float a = prm[0];
    for (int gg = 0; gg < 136; ++gg) {
      int g = gbase + gg;
      float gv = XMIN_F + (float)g * STEP_F;
      float dx = gv - xo;
      float w = __expf(-(dx*dx) * a);
      float4 h0 = h4[g*2], h1 = h4[g*2+1];
      accm[0] += h0.x * w; accm[1] += h0.y * w;
      accm[2] += h0.z * w; accm[3] += h0.w * w;
      accm[4] += h1.x * w; accm[5] += h1.y * w;
      accm[6] += h1.z * w; accm[7] += h1.w * w;
    }
  } else {
    float am[8], asg[8];
    #pragma unroll
    for (int c = 0; c < 8; ++c) { am[c] = prm[c]; asg[c] = prm[8 + c]; }
    for (int gg = 0; gg < 136; ++gg) {
      int g = gbase + gg;
      float gv = XMIN_F + (float)g * STEP_F;
      float dx = gv - xo;
      float d = dx * dx;
      #pragma unroll
      for (int c = 0; c < 8; ++c) {
        float hv = hb[g*8 + c];
        accm[c] += hv * __expf(-d * am[c]);
        accs[c] += hv * __expf(-d * asg[c]);
      }
    }
  }
  __shared__ float red[256 * 17];
  #pragma unroll
  for (int c = 0; c < 8; ++c) {
    red[t*17 + c] = accm[c];
    if (!fused) red[t*17 + 8 + c] = accs[c];
  }
  __syncthreads();
  if (t < 64) {
    int mm = blockIdx.x * 64 + t;
    float fm[8], fs[8];
    #pragma unroll
    for (int c = 0; c < 8; ++c) {
      fm[c] = red[t*17+c] + red[(t+64)*17+c] + red[(t+128)*17+c] + red[(t+192)*17+c];
    }
    if (fused) {
      #pragma unroll
      for (int c = 0; c < 8; ++c) fs[c] = fm[c];
    } else {
      #pragma unroll
      for (int c = 0; c < 8; ++c) {
        fs[c] = red[t*17+8+c] + red[(t+64)*17+8+c] + red[(t+128)*17+8+c] + red[(t+192)*17+8+c];
      }
    }
    float mv = mean_b[0];
    #pragma unroll
    for (int c = 0; c < 8; ++c) mv += fm[c] * mean_W[c];
    mean_out[(size_t)b * MPTS + mm] = mv;
    float cmv = prm[88];
    #pragma unroll
    for (int c = 0; c < 8; ++c) cmv += fs[c] * prm[80 + c];
    cm[(size_t)b * MPTS + mm] = cmv;
    size_t base = ((size_t)b * MPTS + mm) * 8;
    #pragma unroll
    for (int c2 = 0; c2 < 8; ++c2) {
      float p = prm[80 + c2];
      #pragma unroll
      for (int c = 0; c < 8; ++c) p += fs[c] * prm[16 + c*8 + c2];
      Pv[base + c2] = p;
    }
    float* fp = fSt + (size_t)b * 8 * MPTS + mm;
    #pragma unroll
    for (int c = 0; c < 8; ++c) fp[c * MPTS] = fs[c];
  }
}

__global__ __launch_bounds__(256) void k_cov(
    const float* __restrict__ fSt, const float* __restrict__ Pv,
    const float* __restrict__ cm, const float* __restrict__ noise_scale,
    float* __restrict__ cov) {
  int b = blockIdx.y, t = threadIdx.x;
  int half = blockIdx.x & 1, rt = blockIdx.x >> 1;
  int col = half * 1024 + 4 * t;
  int row0 = rt * 8;
  float noise = __expf(noise_scale[0]);
  v4f fn[8];
  const float* fb = fSt + (size_t)b * 8 * MPTS;
  #pragma unroll
  for (int c = 0; c < 8; ++c)
    fn[c] = *(const v4f*)(fb + c * MPTS + col);
  const float* Pr = Pv + ((size_t)b * MPTS + row0) * 8;
  const float* Cr = cm + (size_t)b * MPTS + row0;
  v4f o[8];
  #pragma unroll
  for (int i = 0; i < 8; ++i) {
    float cc = Cr[i];
    float a0 = cc, a1 = cc, a2 = cc, a3 = cc;
    #pragma unroll
    for (int c = 0; c < 8; ++c) {
      float p = Pr[i * 8 + c];
      a0 += p * fn[c].x; a1 += p * fn[c].y;
      a2 += p * fn[c].z; a3 += p * fn[c].w;
    }
    int mg = row0 + i;
    if (mg == col)     a0 += noise;
    if (mg == col + 1) a1 += noise;
    if (mg == col + 2) a2 += noise;
    if (mg == col + 3) a3 += noise;
    o[i].x = a0; o[i].y = a1; o[i].z = a2; o[i].w = a3;
  }
  #pragma unroll
  for (int i = 0; i < 8; ++i) {
    v4f* dst = (v4f*)(cov + ((size_t)b * MPTS + row0 + i) * MPTS + col);
    __builtin_nontemporal_store(o[i], dst);
  }
}

extern "C" void kernel_launch(void* const* d_in, const int* in_sizes, int n_in,
                              void* d_out, int out_size, void* d_ws, size_t ws_size,
                              hipStream_t stream) {
  const float* x          = (const float*)d_in[0];
  const float* y          = (const float*)d_in[1];
  const float* x_out      = (const float*)d_in[2];
  const float* enc_sigma  = (const float*)d_in[3];
  const float* enc_W      = (const float*)d_in[4];
  const float* enc_b      = (const float*)d_in[5];
  const float* rho_W      = (const float*)d_in[6];
  const float* rho_b      = (const float*)d_in[7];
  const float* mean_sigma = (const float*)d_in[8];
  const float* mean_W     = (const float*)d_in[9];
  const float* mean_b     = (const float*)d_in[10];
  const float* sig_sigma  = (const float*)d_in[11];
  const float* sig_W      = (const float*)d_in[12];
  const float* sig_b      = (const float*)d_in[13];
  const float* noise_sc   = (const float*)d_in[14];

  float* wsf = (float*)d_ws;
  float* prm  = wsf + PRM_OFF;
  float* hbuf = wsf + H_OFF;
  float* fStb = wsf + FST_OFF;
  float* Pb   = wsf + P_OFF;
  float* cmb  = wsf + CM_OFF;

  float* mean_out = (float*)d_out;                   // B*M floats
  float* cov_out  = mean_out + (size_t)BATCH * MPTS; // B*M*M floats

  // one-time: size cooperative grid from occupancy (co-residency guaranteed)
  static int s_grid = 0;
  if (s_grid == 0) {
    int bpc = 0;
    hipError_t qe = hipOccupancyMaxActiveBlocksPerMultiprocessor(&bpc, k_fused, 256, 0);
    int g = (qe == hipSuccess && bpc > 0) ? bpc * 256 : 0;
    if (g > 2048) g = 2048;
    s_grid = (g >= 64) ? g : -1;
  }

  if (s_grid > 0) {
    void* args[] = {(void*)&x, (void*)&y, (void*)&x_out, (void*)&enc_sigma,
                    (void*)&enc_W, (void*)&enc_b, (void*)&rho_W, (void*)&rho_b,
                    (void*)&mean_sigma, (void*)&mean_W, (void*)&mean_b,
                    (void*)&sig_sigma, (void*)&sig_W, (void*)&sig_b,
                    (void*)&noise_sc, (void*)&prm, (void*)&hbuf, (void*)&fStb,
                    (void*)&Pb, (void*)&cmb, (void*)&mean_out, (void*)&cov_out};
    hipError_t e = hipLaunchCooperativeKernel((void*)k_fused, dim3(s_grid),
                                              dim3(256), args, 0, stream);
    if (e == hipSuccess) return;
    s_grid = -1;   // cooperative not viable -> fall back permanently
  }

  k_encode<<<dim3(69, BATCH), 256, 0, stream>>>(
      x, y, enc_sigma, enc_W, enc_b, rho_W, rho_b,
      mean_sigma, sig_sigma, sig_W, sig_b, prm, hbuf);
  k_feat<<<dim3(MPTS/64, BATCH), 256, 0, stream>>>(x_out, mean_W, mean_b, prm,
                                                   hbuf, mean_out, fStb, Pb, cmb);
  k_cov<<<dim3(2 * (MPTS/8), BATCH), 256, 0, stream>>>(fStb, Pb, cmb, noise_sc,
                                                       cov_out);
}

// Round 10
// 318.355 us; speedup vs baseline: 1.0558x; 1.0558x over previous
//
#include <hip/hip_runtime.h>
#include <math.h>

// Problem constants (from reference)
#define GRID_N 544          // NUM_GRID = ceil(128*4.2/16)*16 = 68 * 8
#define BATCH  8
#define NPTS   2048
#define MPTS   2048
#define XMIN_F (-2.1f)
#define STEP_F (4.2f / 543.0f)   // linspace step, endpoint inclusive

typedef float v4f __attribute__((ext_vector_type(4)));

// Workspace layout (floats):
#define PRM_OFF 0
#define H_OFF   128
#define FST_OFF (H_OFF + BATCH*GRID_N*8)
#define P_OFF   (FST_OFF + BATCH*8*MPTS)
#define CM_OFF  (P_OFF + BATCH*MPTS*8)
#define CNT_OFF (CM_OFF + BATCH*MPTS)       // 4 uints: {cnt1,flag1,cnt2,flag2}

// R10 theory: R2 and R9 fused kernels ran IDENTICAL 290.3us with totally
// different phase bodies -> duration dominated by the 2 cg::this_grid()
// .sync() calls (~115us each).  Replace with minimal hand barrier:
// thread-0-only atomicAdd arrival + flag spin, __threadfence() for the
// device-scope release/acquire (emits per-XCD L2 wb/inv).  Cooperative
// launch kept ONLY for co-residency (spin safety).  Counters zeroed by
// 16B hipMemsetAsync per call (ws is poisoned between iterations).
// Phase C: two 4-row chunks -> ~58 live VGPRs, no spill at VGPR=64.

__device__ __forceinline__ void grid_barrier(unsigned* cnt, unsigned* flag,
                                             int nb, int t) {
  __syncthreads();
  if (t == 0) {
    __threadfence();                       // release: L2 writeback (per XCD)
    unsigned old = atomicAdd(cnt, 1u);
    if (old == (unsigned)nb - 1u) {
      atomicExch(flag, 1u);
    } else {
      while (atomicAdd(flag, 0u) == 0u) {  // device-scope load
        __builtin_amdgcn_s_sleep(2);
      }
    }
    __threadfence();                       // acquire: L2/L1 invalidate
  }
  __syncthreads();
}

__global__ __launch_bounds__(256, 2) void k_fused(
    const float* __restrict__ x, const float* __restrict__ y,
    const float* __restrict__ x_out,
    const float* __restrict__ enc_sigma, const float* __restrict__ enc_W,
    const float* __restrict__ enc_b, const float* __restrict__ rho_W,
    const float* __restrict__ rho_b, const float* __restrict__ mean_sigma,
    const float* __restrict__ mean_W, const float* __restrict__ mean_b,
    const float* __restrict__ sig_sigma, const float* __restrict__ sig_W,
    const float* __restrict__ sig_b, const float* __restrict__ noise_scale,
    float* __restrict__ prm, float* __restrict__ h_out,
    float* __restrict__ fSt, float* __restrict__ Pv, float* __restrict__ cm,
    unsigned* __restrict__ bar,
    float* __restrict__ mean_out, float* __restrict__ cov) {
  const int bid = blockIdx.x, t = threadIdx.x, nb = gridDim.x;
  __shared__ float sbuf[256 * 17];   // E: xs/ys (16KB); F: red (17.4KB)

  // ---------------- phase E: encoder (545 units) ----------------
  for (int u = bid; u < 545; u += nb) {
    if (u == 544) {
      float* part = sbuf;
      {
        int pair = t >> 2, q = t & 3;
        int i = pair >> 3, j = pair & 7;
        float s = 0.f;
        int k0 = q * 256;
        for (int k = k0; k < k0 + 256; ++k) s += sig_W[i*1024+k] * sig_W[j*1024+k];
        part[t] = s;
        __syncthreads();
        if (q == 0) prm[16 + pair] = part[t] + part[t+1] + part[t+2] + part[t+3];
        __syncthreads();
      }
      {
        int ch = t >> 5, lane = t & 31;
        float s = 0.f;
        for (int k = lane; k < 1024; k += 32) s += sig_W[ch*1024+k] * sig_b[k];
        part[t] = s;
        __syncthreads();
        if (lane == 0) {
          float acc = 0.f;
          for (int k = 0; k < 32; ++k) acc += part[(ch<<5)+k];
          prm[80 + ch] = acc;
        }
        __syncthreads();
      }
      if (t < 32) {
        float v = 0.f;
        for (int k = t; k < 1024; k += 32) v += sig_b[k] * sig_b[k];
        part[t] = v;
      }
      __syncthreads();
      if (t == 0) {
        float v = 0.f;
        for (int k = 0; k < 32; ++k) v += part[k];
        prm[88] = v;
      } else if (t == 1) {
        bool f = true;
        for (int c = 0; c < 8; ++c) {
          prm[c]     = 0.5f * __expf(-2.f * mean_sigma[c]);
          prm[8 + c] = 0.5f * __expf(-2.f * sig_sigma[c]);
          if (mean_sigma[c] != mean_sigma[0] || sig_sigma[c] != sig_sigma[0]) f = false;
        }
        if (mean_sigma[0] != sig_sigma[0]) f = false;
        prm[89] = f ? 1.f : 0.f;
      }
      __syncthreads();
    } else {
      int b = u / 68, gt = u - b * 68;
      float* xs = sbuf;
      float* ys = sbuf + NPTS;
      __syncthreads();
      {
        const float4* x4 = (const float4*)(x + (size_t)b * NPTS);
        const float4* y4 = (const float4*)(y + (size_t)b * NPTS);
        float4* xs4 = (float4*)xs;
        float4* ys4 = (float4*)ys;
        #pragma unroll
        for (int i = 0; i < 2; ++i) {
          int n = i * 256 + t;
          xs4[n] = x4[n];
          ys4[n] = y4[n];
        }
      }
      __syncthreads();
      float es0 = enc_sigma[0], es1 = enc_sigma[1];
      float a0 = 0.5f * __expf(-2.f * es0);
      float a1 = 0.5f * __expf(-2.f * es1);
      bool uni = (es0 == es1);
      int wave = t >> 6, lane = t & 63;
      #pragma unroll 1
      for (int gi = 0; gi < 2; ++gi) {
        int g = gt * 8 + wave * 2 + gi;
        float gv = XMIN_F + (float)g * STEP_F;
        float s0 = 0.f, s1 = 0.f;
        #pragma unroll 4
        for (int k = 0; k < 32; ++k) {
          int n = lane + (k << 6);
          float xv = xs[n], yv = ys[n];
          float dx = xv - gv;
          float d = dx * dx;
          float w = __expf(-d * a0);
          s0 += w;
          s1 += yv * (uni ? w : __expf(-d * a1));
        }
        #pragma unroll
        for (int off = 32; off > 0; off >>= 1) {
          s0 += __shfl_down(s0, off);
          s1 += __shfl_down(s1, off);
        }
        if (lane == 0) {
          float den = s0;
          float F0 = den, F1 = s1 / (den + 1e-8f);
          float hh[8];
          #pragma unroll
          for (int jj = 0; jj < 8; ++jj) {
            float z = F0 * enc_W[jj] + F1 * enc_W[8 + jj] + enc_b[jj];
            hh[jj] = 1.f / (1.f + __expf(-z));
          }
          #pragma unroll
          for (int jj = 0; jj < 8; ++jj) {
            float v = rho_b[jj];
            #pragma unroll
            for (int ii = 0; ii < 8; ++ii) v += hh[ii] * rho_W[ii*8 + jj];
            h_out[((size_t)b * GRID_N + g) * 8 + jj] = v;
          }
        }
      }
    }
  }
  grid_barrier(bar + 0, bar + 1, nb, t);

  // ---------------- phase F: decoder feats (256 units) ----------------
  bool fsc = prm[89] != 0.f;
  for (int u = bid; u < 256; u += nb) {
    int b = u >> 5, mblk = u & 31;
    int ml = t & 63, slice = t >> 6;
    int m = mblk * 64 + ml;
    float xo = x_out[(size_t)b * MPTS + m];
    float accm[8] = {0,0,0,0,0,0,0,0};
    float accs[8] = {0,0,0,0,0,0,0,0};
    const float* hb = h_out + (size_t)b * GRID_N * 8;
    const float4* h4 = (const float4*)hb;
    int gbase = slice * 136;
    if (fsc) {
      float a = prm[0];
      for (int gg = 0; gg < 136; ++gg) {
        int g = gbase + gg;
        float gv = XMIN_F + (float)g * STEP_F;
        float dx = gv - xo;
        float w = __expf(-(dx*dx) * a);
        float4 h0 = h4[g*2], h1 = h4[g*2+1];
        accm[0] += h0.x * w; accm[1] += h0.y * w;
        accm[2] += h0.z * w; accm[3] += h0.w * w;
        accm[4] += h1.x * w; accm[5] += h1.y * w;
        accm[6] += h1.z * w; accm[7] += h1.w * w;
      }
    } else {
      float am[8], asg[8];
      #pragma unroll
      for (int c = 0; c < 8; ++c) { am[c] = prm[c]; asg[c] = prm[8 + c]; }
      for (int gg = 0; gg < 136; ++gg) {
        int g = gbase + gg;
        float gv = XMIN_F + (float)g * STEP_F;
        float dx = gv - xo;
        float d = dx * dx;
        #pragma unroll
        for (int c = 0; c < 8; ++c) {
          float hv = hb[g*8 + c];
          accm[c] += hv * __expf(-d * am[c]);
          accs[c] += hv * __expf(-d * asg[c]);
        }
      }
    }
    __syncthreads();
    #pragma unroll
    for (int c = 0; c < 8; ++c) {
      sbuf[t*17 + c] = accm[c];
      if (!fsc) sbuf[t*17 + 8 + c] = accs[c];
    }
    __syncthreads();
    if (t < 64) {
      int mm = mblk * 64 + t;
      float fm[8], fs[8];
      #pragma unroll
      for (int c = 0; c < 8; ++c) {
        fm[c] = sbuf[t*17+c] + sbuf[(t+64)*17+c] + sbuf[(t+128)*17+c] + sbuf[(t+192)*17+c];
      }
      if (fsc) {
        #pragma unroll
        for (int c = 0; c < 8; ++c) fs[c] = fm[c];
      } else {
        #pragma unroll
        for (int c = 0; c < 8; ++c) {
          fs[c] = sbuf[t*17+8+c] + sbuf[(t+64)*17+8+c] + sbuf[(t+128)*17+8+c] + sbuf[(t+192)*17+8+c];
        }
      }
      float mv = mean_b[0];
      #pragma unroll
      for (int c = 0; c < 8; ++c) mv += fm[c] * mean_W[c];
      mean_out[(size_t)b * MPTS + mm] = mv;
      float cmv = prm[88];
      #pragma unroll
      for (int c = 0; c < 8; ++c) cmv += fs[c] * prm[80 + c];
      cm[(size_t)b * MPTS + mm] = cmv;
      size_t base = ((size_t)b * MPTS + mm) * 8;
      #pragma unroll
      for (int c2 = 0; c2 < 8; ++c2) {
        float p = prm[80 + c2];
        #pragma unroll
        for (int c = 0; c < 8; ++c) p += fs[c] * prm[16 + c*8 + c2];
        Pv[base + c2] = p;
      }
      float* fp = fSt + (size_t)b * 8 * MPTS + mm;
      #pragma unroll
      for (int c = 0; c < 8; ++c) fp[c * MPTS] = fs[c];
    }
  }
  grid_barrier(bar + 2, bar + 3, nb, t);

  // ---------------- phase C: covariance (4096 units, 2x4-row chunks) ------
  float noise = __expf(noise_scale[0]);
  for (int u = bid; u < BATCH * 512; u += nb) {
    int b = u >> 9, idx = u & 511;
    int half = idx & 1, rt = idx >> 1;
    int col = half * 1024 + 4 * t;
    int row0 = rt * 8;
    v4f fn[8];
    const float* fb_ = fSt + (size_t)b * 8 * MPTS;
    #pragma unroll
    for (int c = 0; c < 8; ++c)
      fn[c] = *(const v4f*)(fb_ + c * MPTS + col);
    const float* Pr = Pv + ((size_t)b * MPTS + row0) * 8;
    const float* Cr = cm + (size_t)b * MPTS + row0;
    #pragma unroll
    for (int h8 = 0; h8 < 2; ++h8) {
      v4f o[4];
      #pragma unroll
      for (int i = 0; i < 4; ++i) {
        int mi = h8 * 4 + i;
        float cc = Cr[mi];
        float a0 = cc, a1 = cc, a2 = cc, a3 = cc;
        #pragma unroll
        for (int c = 0; c < 8; ++c) {
          float p = Pr[mi * 8 + c];
          a0 += p * fn[c].x; a1 += p * fn[c].y;
          a2 += p * fn[c].z; a3 += p * fn[c].w;
        }
        int mg = row0 + mi;
        if (mg == col)     a0 += noise;
        if (mg == col + 1) a1 += noise;
        if (mg == col + 2) a2 += noise;
        if (mg == col + 3) a3 += noise;
        o[i].x = a0; o[i].y = a1; o[i].z = a2; o[i].w = a3;
      }
      #pragma unroll
      for (int i = 0; i < 4; ++i) {
        int mi = h8 * 4 + i;
        v4f* dst = (v4f*)(cov + ((size_t)b * MPTS + row0 + mi) * MPTS + col);
        __builtin_nontemporal_store(o[i], dst);
      }
    }
  }
}

// =================================================================
// Fallback 3-kernel path (best-measured class, ~211us)
// =================================================================
__global__ __launch_bounds__(256) void k_encode(
    const float* __restrict__ x, const float* __restrict__ y,
    const float* __restrict__ enc_sigma,
    const float* __restrict__ enc_W, const float* __restrict__ enc_b,
    const float* __restrict__ rho_W, const float* __restrict__ rho_b,
    const float* __restrict__ mean_sigma, const float* __restrict__ sig_sigma,
    const float* __restrict__ sig_W, const float* __restrict__ sig_b,
    float* __restrict__ prm, float* __restrict__ h_out) {
  int b = blockIdx.y, gt = blockIdx.x, t = threadIdx.x;
  if (gt == 68) {
    if (b != 0) return;
    __shared__ float part[256];
    {
      int pair = t >> 2, q = t & 3;
      int i = pair >> 3, j = pair & 7;
      float s = 0.f;
      int k0 = q * 256;
      for (int k = k0; k < k0 + 256; ++k) s += sig_W[i*1024+k] * sig_W[j*1024+k];
      part[t] = s;
      __syncthreads();
      if (q == 0) prm[16 + pair] = part[t] + part[t+1] + part[t+2] + part[t+3];
      __syncthreads();
    }
    {
      int ch = t >> 5, lane = t & 31;
      float s = 0.f;
      for (int k = lane; k < 1024; k += 32) s += sig_W[ch*1024+k] * sig_b[k];
      part[t] = s;
      __syncthreads();
      if (lane == 0) {
        float acc = 0.f;
        for (int k = 0; k < 32; ++k) acc += part[(ch<<5)+k];
        prm[80 + ch] = acc;
      }
      __syncthreads();
    }
    if (t < 32) {
      float v = 0.f;
      for (int k = t; k < 1024; k += 32) v += sig_b[k] * sig_b[k];
      part[t] = v;
    }
    __syncthreads();
    if (t == 0) {
      float v = 0.f;
      for (int k = 0; k < 32; ++k) v += part[k];
      prm[88] = v;
    } else if (t == 1) {
      bool f = true;
      for (int c = 0; c < 8; ++c) {
        prm[c]     = 0.5f * __expf(-2.f * mean_sigma[c]);
        prm[8 + c] = 0.5f * __expf(-2.f * sig_sigma[c]);
        if (mean_sigma[c] != mean_sigma[0] || sig_sigma[c] != sig_sigma[0]) f = false;
      }
      if (mean_sigma[0] != sig_sigma[0]) f = false;
      prm[89] = f ? 1.f : 0.f;
    }
    return;
  }
  __shared__ float xs[NPTS], ys[NPTS];
  {
    const float4* x4 = (const float4*)(x + (size_t)b * NPTS);
    const float4* y4 = (const float4*)(y + (size_t)b * NPTS);
    float4* xs4 = (float4*)xs;
    float4* ys4 = (float4*)ys;
    #pragma unroll
    for (int i = 0; i < 2; ++i) {
      int n = i * 256 + t;
      xs4[n] = x4[n];
      ys4[n] = y4[n];
    }
  }
  __syncthreads();
  float es0 = enc_sigma[0], es1 = enc_sigma[1];
  float a0 = 0.5f * __expf(-2.f * es0);
  float a1 = 0.5f * __expf(-2.f * es1);
  bool uni = (es0 == es1);
  int wave = t >> 6, lane = t & 63;
  #pragma unroll 1
  for (int gi = 0; gi < 2; ++gi) {
    int g = gt * 8 + wave * 2 + gi;
    float gv = XMIN_F + (float)g * STEP_F;
    float s0 = 0.f, s1 = 0.f;
    #pragma unroll 4
    for (int k = 0; k < 32; ++k) {
      int n = lane + (k << 6);
      float xv = xs[n], yv = ys[n];
      float dx = xv - gv;
      float d = dx * dx;
      float w = __expf(-d * a0);
      s0 += w;
      s1 += yv * (uni ? w : __expf(-d * a1));
    }
    #pragma unroll
    for (int off = 32; off > 0; off >>= 1) {
      s0 += __shfl_down(s0, off);
      s1 += __shfl_down(s1, off);
    }
    if (lane == 0) {
      float den = s0;
      float F0 = den, F1 = s1 / (den + 1e-8f);
      float hh[8];
      #pragma unroll
      for (int jj = 0; jj < 8; ++jj) {
        float z = F0 * enc_W[jj] + F1 * enc_W[8 + jj] + enc_b[jj];
        hh[jj] = 1.f / (1.f + __expf(-z));
      }
      #pragma unroll
      for (int jj = 0; jj < 8; ++jj) {
        float v = rho_b[jj];
        #pragma unroll
        for (int ii = 0; ii < 8; ++ii) v += hh[ii] * rho_W[ii*8 + jj];
        h_out[((size_t)b * GRID_N + g) * 8 + jj] = v;
      }
    }
  }
}

__global__ __launch_bounds__(256) void k_feat(
    const float* __restrict__ x_out, const float* __restrict__ mean_W,
    const float* __restrict__ mean_b, const float* __restrict__ prm,
    const float* __restrict__ h, float* __restrict__ mean_out,
    float* __restrict__ fSt, float* __restrict__ Pv, float* __restrict__ cm) {
  int b = blockIdx.y, t = threadIdx.x;
  int ml = t & 63, slice = t >> 6;
  int m = blockIdx.x * 64 + ml;
  float xo = x_out[(size_t)b * MPTS + m];
  bool fused = prm[89] != 0.f;
  float accm[8] = {0,0,0,0,0,0,0,0};
  float accs[8] = {0,0,0,0,0,0,0,0};
  const float* hb = h + (size_t)b * GRID_N * 8;
  const float4* h4 = (const float4*)hb;
  int gbase = slice * 136;
  if (fused) {
    float a = prm[0];
    for (int gg = 0; gg < 136; ++gg) {
      int g = gbase + gg;
      float gv = XMIN_F + (float)g * STEP_F;
      float dx = gv - xo;
      float w = __expf(-(dx*dx) * a);
      float4 h0 = h4[g*2], h1 = h4[g*2+1];
      accm[0] += h0.x * w; accm[1] += h0.y * w;
      accm[2] += h0.z * w; accm[3] += h0.w * w;
      accm[4] += h1.x * w; accm[5] += h1.y * w;
      accm[6] += h1.z * w; accm[7] += h1.w * w;
    }
  } else {
    float am[8], asg[8];
    #pragma unroll
    for (int c = 0; c < 8; ++c) { am[c] = prm[c]; asg[c] = prm[8 + c]; }
    for (int gg = 0; gg < 136; ++gg) {
      int g = gbase + gg;
      float gv = XMIN_F + (float)g * STEP_F;
      float dx = gv - xo;
      float d = dx * dx;
      #pragma unroll
      for (int c = 0; c < 8; ++c) {
        float hv = hb[g*8 + c];
        accm[c] += hv * __expf(-d * am[c]);
        accs[c] += hv * __expf(-d * asg[c]);
      }
    }
  }
  __shared__ float red[256 * 17];
  #pragma unroll
  for (int c = 0; c < 8; ++c) {
    red[t*17 + c] = accm[c];
    if (!fused) red[t*17 + 8 + c] = accs[c];
  }
  __syncthreads();
  if (t < 64) {
    int mm = blockIdx.x * 64 + t;
    float fm[8], fs[8];
    #pragma unroll
    for (int c = 0; c < 8; ++c) {
      fm[c] = red[t*17+c] + red[(t+64)*17+c] + red[(t+128)*17+c] + red[(t+192)*17+c];
    }
    if (fused) {
      #pragma unroll
      for (int c = 0; c < 8; ++c) fs[c] = fm[c];
    } else {
      #pragma unroll
      for (int c = 0; c < 8; ++c) {
        fs[c] = red[t*17+8+c] + red[(t+64)*17+8+c] + red[(t+128)*17+8+c] + red[(t+192)*17+8+c];
      }
    }
    float mv = mean_b[0];
    #pragma unroll
    for (int c = 0; c < 8; ++c) mv += fm[c] * mean_W[c];
    mean_out[(size_t)b * MPTS + mm] = mv;
    float cmv = prm[88];
    #pragma unroll
    for (int c = 0; c < 8; ++c) cmv += fs[c] * prm[80 + c];
    cm[(size_t)b * MPTS + mm] = cmv;
    size_t base = ((size_t)b * MPTS + mm) * 8;
    #pragma unroll
    for (int c2 = 0; c2 < 8; ++c2) {
      float p = prm[80 + c2];
      #pragma unroll
      for (int c = 0; c < 8; ++c) p += fs[c] * prm[16 + c*8 + c2];
      Pv[base + c2] = p;
    }
    float* fp = fSt + (size_t)b * 8 * MPTS + mm;
    #pragma unroll
    for (int c = 0; c < 8; ++c) fp[c * MPTS] = fs[c];
  }
}

__global__ __launch_bounds__(256) void k_cov(
    const float* __restrict__ fSt, const float* __restrict__ Pv,
    const float* __restrict__ cm, const float* __restrict__ noise_scale,
    float* __restrict__ cov) {
  int b = blockIdx.y, t = threadIdx.x;
  int half = blockIdx.x & 1, rt = blockIdx.x >> 1;
  int col = half * 1024 + 4 * t;
  int row0 = rt * 8;
  float noise = __expf(noise_scale[0]);
  v4f fn[8];
  const float* fb = fSt + (size_t)b * 8 * MPTS;
  #pragma unroll
  for (int c = 0; c < 8; ++c)
    fn[c] = *(const v4f*)(fb + c * MPTS + col);
  const float* Pr = Pv + ((size_t)b * MPTS + row0) * 8;
  const float* Cr = cm + (size_t)b * MPTS + row0;
  v4f o[8];
  #pragma unroll
  for (int i = 0; i < 8; ++i) {
    float cc = Cr[i];
    float a0 = cc, a1 = cc, a2 = cc, a3 = cc;
    #pragma unroll
    for (int c = 0; c < 8; ++c) {
      float p = Pr[i * 8 + c];
      a0 += p * fn[c].x; a1 += p * fn[c].y;
      a2 += p * fn[c].z; a3 += p * fn[c].w;
    }
    int mg = row0 + i;
    if (mg == col)     a0 += noise;
    if (mg == col + 1) a1 += noise;
    if (mg == col + 2) a2 += noise;
    if (mg == col + 3) a3 += noise;
    o[i].x = a0; o[i].y = a1; o[i].z = a2; o[i].w = a3;
  }
  #pragma unroll
  for (int i = 0; i < 8; ++i) {
    v4f* dst = (v4f*)(cov + ((size_t)b * MPTS + row0 + i) * MPTS + col);
    __builtin_nontemporal_store(o[i], dst);
  }
}

extern "C" void kernel_launch(void* const* d_in, const int* in_sizes, int n_in,
                              void* d_out, int out_size, void* d_ws, size_t ws_size,
                              hipStream_t stream) {
  const float* x          = (const float*)d_in[0];
  const float* y          = (const float*)d_in[1];
  const float* x_out      = (const float*)d_in[2];
  const float* enc_sigma  = (const float*)d_in[3];
  const float* enc_W      = (const float*)d_in[4];
  const float* enc_b      = (const float*)d_in[5];
  const float* rho_W      = (const float*)d_in[6];
  const float* rho_b      = (const float*)d_in[7];
  const float* mean_sigma = (const float*)d_in[8];
  const float* mean_W     = (const float*)d_in[9];
  const float* mean_b     = (const float*)d_in[10];
  const float* sig_sigma  = (const float*)d_in[11];
  const float* sig_W      = (const float*)d_in[12];
  const float* sig_b      = (const float*)d_in[13];
  const float* noise_sc   = (const float*)d_in[14];

  float* wsf = (float*)d_ws;
  float* prm  = wsf + PRM_OFF;
  float* hbuf = wsf + H_OFF;
  float* fStb = wsf + FST_OFF;
  float* Pb   = wsf + P_OFF;
  float* cmb  = wsf + CM_OFF;
  unsigned* bar = (unsigned*)(wsf + CNT_OFF);

  float* mean_out = (float*)d_out;                   // B*M floats
  float* cov_out  = mean_out + (size_t)BATCH * MPTS; // B*M*M floats

  // one-time: size cooperative grid from occupancy (co-residency guaranteed)
  static int s_grid = 0;
  if (s_grid == 0) {
    int bpc = 0;
    hipError_t qe = hipOccupancyMaxActiveBlocksPerMultiprocessor(&bpc, k_fused, 256, 0);
    int g = (qe == hipSuccess && bpc > 0) ? bpc * 256 : 0;
    if (g > 1024) g = 1024;
    s_grid = (g >= 64) ? g : -1;
  }

  if (s_grid > 0) {
    // zero the 4 barrier words (ws is re-poisoned between iterations)
    hipError_t em = hipMemsetAsync((void*)bar, 0, 16, stream);
    if (em == hipSuccess) {
      void* args[] = {(void*)&x, (void*)&y, (void*)&x_out, (void*)&enc_sigma,
                      (void*)&enc_W, (void*)&enc_b, (void*)&rho_W, (void*)&rho_b,
                      (void*)&mean_sigma, (void*)&mean_W, (void*)&mean_b,
                      (void*)&sig_sigma, (void*)&sig_W, (void*)&sig_b,
                      (void*)&noise_sc, (void*)&prm, (void*)&hbuf, (void*)&fStb,
                      (void*)&Pb, (void*)&cmb, (void*)&bar,
                      (void*)&mean_out, (void*)&cov_out};
      hipError_t e = hipLaunchCooperativeKernel((void*)k_fused, dim3(s_grid),
                                                dim3(256), args, 0, stream);
      if (e == hipSuccess) return;
    }
    s_grid = -1;   // cooperative not viable -> fall back permanently
  }

  k_encode<<<dim3(69, BATCH), 256, 0, stream>>>(
      x, y, enc_sigma, enc_W, enc_b, rho_W, rho_b,
      mean_sigma, sig_sigma, sig_W, sig_b, prm, hbuf);
  k_feat<<<dim3(MPTS/64, BATCH), 256, 0, stream>>>(x_out, mean_W, mean_b, prm,
                                                   hbuf, mean_out, fStb, Pb, cmb);
  k_cov<<<dim3(2 * (MPTS/8), BATCH), 256, 0, stream>>>(fStb, Pb, cmb, noise_sc,
                                                       cov_out);
}